// Round 6
// baseline (449.838 us; speedup 1.0000x reference)
//
#include <hip/hip_runtime.h>
#include <hip/hip_bf16.h>

// Shapes (fixed by reference): B=32, N=12, S=512, D=256, A=96
#define B_ 32
#define N_ 12
#define S_ 512
#define D_ 256
#define A_ 96

typedef __attribute__((ext_vector_type(8))) short short8;   // 8 bf16 (4 VGPRs)
typedef __attribute__((ext_vector_type(4))) float float4v;  // MFMA acc

// fp32 -> bf16 round-to-nearest-even (data has no NaN/Inf)
static __device__ __forceinline__ ushort f2bf(float f) {
  union { float f; unsigned u; } a;
  a.f = f;
  return (ushort)((a.u + 0x7FFFu + ((a.u >> 16) & 1u)) >> 16);
}

// ---------------------------------------------------------------------------
// Kernel 1: qk = emb @ Wqk + bqk  [N,S,D] fp32 (for kernel 2), and
//           q = softmax(qk, d) written bf16 [n][s][d].
// 8 s-rows per block: Wqk loaded once per 8 rows, emb staged transposed.
// ---------------------------------------------------------------------------
__global__ __launch_bounds__(256) void k_qk_softmax_q(
    const float* __restrict__ emb, const float* __restrict__ Wqk,
    const float* __restrict__ bqk, float* __restrict__ qk,
    ushort* __restrict__ qb) {
  const int blk = blockIdx.x;  // 768 blocks, 8 rows each (rows never straddle n)
  const int tid = threadIdx.x;
  const int d = tid;
  const int wv = tid >> 6, lane = tid & 63;
  __shared__ float seT[A_][8];  // [a][r]
  __shared__ float redm[8][4], reds[8][4];
  const float* ebase = emb + (size_t)blk * 8 * A_;
  for (int k = tid; k < 8 * A_; k += 256) {
    int r = k / A_, a = k - r * A_;
    seT[a][r] = ebase[k];
  }
  __syncthreads();
  float bq = bqk[d];
  float acc[8];
#pragma unroll
  for (int r = 0; r < 8; ++r) acc[r] = bq;
#pragma unroll 8
  for (int a = 0; a < A_; ++a) {
    float w = Wqk[a * D_ + d];
    float4 lo = *(const float4*)(&seT[a][0]);
    float4 hi = *(const float4*)(&seT[a][4]);
    acc[0] = fmaf(lo.x, w, acc[0]);
    acc[1] = fmaf(lo.y, w, acc[1]);
    acc[2] = fmaf(lo.z, w, acc[2]);
    acc[3] = fmaf(lo.w, w, acc[3]);
    acc[4] = fmaf(hi.x, w, acc[4]);
    acc[5] = fmaf(hi.y, w, acc[5]);
    acc[6] = fmaf(hi.z, w, acc[6]);
    acc[7] = fmaf(hi.w, w, acc[7]);
  }
  const size_t obase = (size_t)blk * 8 * D_ + d;
#pragma unroll
  for (int r = 0; r < 8; ++r) qk[obase + r * D_] = acc[r];
  float m[8];
#pragma unroll
  for (int r = 0; r < 8; ++r) {
    m[r] = acc[r];
    for (int off = 32; off; off >>= 1) m[r] = fmaxf(m[r], __shfl_xor(m[r], off));
  }
  if (lane == 0) {
#pragma unroll
    for (int r = 0; r < 8; ++r) redm[r][wv] = m[r];
  }
  __syncthreads();
  float e[8], s[8];
#pragma unroll
  for (int r = 0; r < 8; ++r) {
    float mm = fmaxf(fmaxf(redm[r][0], redm[r][1]),
                     fmaxf(redm[r][2], redm[r][3]));
    e[r] = __expf(acc[r] - mm);
    s[r] = e[r];
    for (int off = 32; off; off >>= 1) s[r] += __shfl_xor(s[r], off);
  }
  if (lane == 0) {
#pragma unroll
    for (int r = 0; r < 8; ++r) reds[r][wv] = s[r];
  }
  __syncthreads();
#pragma unroll
  for (int r = 0; r < 8; ++r) {
    float sum = reds[r][0] + reds[r][1] + reds[r][2] + reds[r][3];
    qb[obase + r * D_] = f2bf(e[r] / sum);
  }
}

// ---------------------------------------------------------------------------
// Kernel 2: kT[n][d][s] = softmax over s of qk[n][s][d], bf16 output.
// Coalesced: block = (16-d chunk, n); float4 loads -> LDS transpose.
// ---------------------------------------------------------------------------
__global__ __launch_bounds__(256) void k_softmax_kT(
    const float* __restrict__ qk, ushort* __restrict__ kTb) {
  const int dc = blockIdx.x * 16;  // d-chunk base (grid.x = 16)
  const int n = blockIdx.y;
  const int tid = threadIdx.x;
  __shared__ float t[16][514];
  const float* base = qk + (size_t)n * S_ * D_ + dc;
#pragma unroll
  for (int it = 0; it < 8; ++it) {  // 2048 float4s: 16 d x 512 s
    int id = it * 256 + tid;
    int d4 = id & 3, s = id >> 2;
    float4 v = *(const float4*)(base + (size_t)s * D_ + 4 * d4);
    t[4 * d4 + 0][s] = v.x;
    t[4 * d4 + 1][s] = v.y;
    t[4 * d4 + 2][s] = v.z;
    t[4 * d4 + 3][s] = v.w;
  }
  __syncthreads();
  const int d = tid >> 4, sg = tid & 15;
  float vv[32];
  float m = -1e30f;
#pragma unroll
  for (int k = 0; k < 32; ++k) {
    vv[k] = t[d][sg + 16 * k];
    m = fmaxf(m, vv[k]);
  }
  for (int off = 1; off < 16; off <<= 1) m = fmaxf(m, __shfl_xor(m, off));
  float sum = 0.0f;
#pragma unroll
  for (int k = 0; k < 32; ++k) {
    vv[k] = __expf(vv[k] - m);
    sum += vv[k];
  }
  for (int off = 1; off < 16; off <<= 1) sum += __shfl_xor(sum, off);
  float inv = 1.0f / sum;
  const size_t ob = ((size_t)n * D_ + dc + d) * S_;
#pragma unroll
  for (int k = 0; k < 32; ++k) kTb[ob + sg + 16 * k] = f2bf(vv[k] * inv);
}

// ---------------------------------------------------------------------------
// Kernel 3: WvT[c][e] = bf16(Wv[e][c])  (tiny: 256x256)
// ---------------------------------------------------------------------------
__global__ __launch_bounds__(256) void k_wvt(const float* __restrict__ Wv,
                                             ushort* __restrict__ WvT) {
  int c = blockIdx.x, e = threadIdx.x;
  WvT[c * D_ + e] = f2bf(Wv[e * D_ + c]);
}

// ---------------------------------------------------------------------------
// Kernel 4: kv0[bz][d][e] = sum_s kT[n][d][s] * value[bz][s][e]  (bf16 MFMA)
// High-occupancy redesign (round-4 fused was 1 block/CU, lockstep, 12% Mfma):
//  - Block = (e-quarter, bz): 1536 blocks; value partitioned EXACTLY once
//    chip-wide (no redundant load/cvt); 3.0 clean rounds at 2 blk/CU.
//  - kT B-fragments loaded DIRECT from global (dwordx4, 16B-aligned;
//    L1/L2-served, each line read by 2 blocks on the same XCD) -> no ldsK.
//  - Only LDS: double-buffered V^T tile [64e][64s] = 18432 B total -> high
//    waves/SIMD; ONE barrier per 64-s step (barrier at iter top separates
//    prev-iter reads of buf[p^1] from this iter's writes -> race-free).
//  - 16B-chunk XOR swizzle ch ^= (e>>3)&7 on BOTH ds_write_b128 and
//    ds_read_b128 -> bank-uniform both sides (T2, both-sides-or-neither).
//  - T14 split: next-tile global loads issued BEFORE the MFMA phase,
//    cvt + ds_write after it (HBM latency hides under MFMA).
// C[m=e][n=d]; 8 waves each own d-range 32w; per-wave acc[4][2] (64e x 32d).
// ---------------------------------------------------------------------------
__global__ __launch_bounds__(512) void k_kv0(
    const ushort* __restrict__ kTb, const float* __restrict__ value,
    ushort* __restrict__ kv0) {
  const int f = blockIdx.x;
  const int wk = (f & 7) * 192 + (f >> 3);  // bijective XCD swizzle (1536%8==0)
  const int eq = wk & 3;   // e-quarter (0..3)
  const int bz = wk >> 2;  // b*N+n
  const int n = bz % N_;
  const int tid = threadIdx.x;
  const int l = tid & 63, w = tid >> 6;  // w: d-range owner (0..7)
  const int lane16 = l & 15, quad = l >> 4;

  __shared__ ushort ldsV[2][64 * 72];  // V^T tile, dbuf, swizzled 16B chunks

  // staging role: thread -> (e row, s-chunk of 8)
  const int se = tid & 63;
  const int sch = tid >> 6;                       // 0..7
  const int schs = (sch ^ ((se >> 3) & 7)) << 3;  // swizzled ushort offset
  const float* vbase = value + (size_t)bz * S_ * D_ + eq * 64 + se;
  const ushort* kTbase = kTb + (size_t)n * D_ * S_ + (w * 32) * S_;

  float4v acc[4][2];
#pragma unroll
  for (int i = 0; i < 4; ++i)
#pragma unroll
    for (int j = 0; j < 2; ++j) acc[i][j] = (float4v)0.0f;

  union Pack { ushort u[8]; uint4 v; };

  // prologue: stage s-tile 0 into buf 0
  {
    float f0[8];
#pragma unroll
    for (int t = 0; t < 8; ++t) f0[t] = vbase[(size_t)(sch * 8 + t) * D_];
    Pack pk;
#pragma unroll
    for (int t = 0; t < 8; ++t) pk.u[t] = f2bf(f0[t]);
    *(uint4*)(&ldsV[0][se * 72 + schs]) = pk.v;
  }

  int p = 0;
  for (int sc = 0; sc < S_; sc += 64) {
    __syncthreads();  // buf[p] ready; prev reads of buf[p^1] complete
    // issue next-tile global loads early (latency hides under MFMA)
    float fs[8];
    const bool more = (sc + 64 < S_);
    if (more) {
#pragma unroll
      for (int t = 0; t < 8; ++t)
        fs[t] = vbase[(size_t)(sc + 64 + sch * 8 + t) * D_];
    }
    // compute from buf[p]: a from LDS (swizzled), b direct from global kT
#pragma unroll
    for (int kc = 0; kc < 64; kc += 32) {
      const int ko = kc + quad * 8;
      const int chr = ko >> 3;
      short8 a[4], b[2];
#pragma unroll
      for (int i = 0; i < 4; ++i) {
        int er = i * 16 + lane16;
        a[i] = *(const short8*)(
            &ldsV[p][er * 72 + ((chr ^ ((er >> 3) & 7)) << 3)]);
      }
#pragma unroll
      for (int j = 0; j < 2; ++j)
        b[j] = *(const short8*)(kTbase + (j * 16 + lane16) * S_ + sc + ko);
#pragma unroll
      for (int i = 0; i < 4; ++i)
#pragma unroll
        for (int j = 0; j < 2; ++j)
          acc[i][j] = __builtin_amdgcn_mfma_f32_16x16x32_bf16(a[i], b[j],
                                                              acc[i][j], 0, 0, 0);
    }
    // write next tile into buf[p^1]
    if (more) {
      Pack pk;
#pragma unroll
      for (int t = 0; t < 8; ++t) pk.u[t] = f2bf(fs[t]);
      *(uint4*)(&ldsV[p ^ 1][se * 72 + schs]) = pk.v;
    }
    p ^= 1;
  }
  // epilogue: m = e = eq*64 + i*16 + quad*4 + r; n = d = w*32 + j*16 + lane16
  ushort* obase = kv0 + (size_t)bz * D_ * D_;
#pragma unroll
  for (int i = 0; i < 4; ++i) {
#pragma unroll
    for (int j = 0; j < 2; ++j) {
      int d = w * 32 + j * 16 + lane16;
      int e0 = eq * 64 + i * 16 + quad * 4;
      ushort4 pk;
      pk.x = f2bf(acc[i][j][0]);
      pk.y = f2bf(acc[i][j][1]);
      pk.z = f2bf(acc[i][j][2]);
      pk.w = f2bf(acc[i][j][3]);
      *(ushort4*)(obase + d * D_ + e0) = pk;
    }
  }
}

// ---------------------------------------------------------------------------
// Kernel 5: IN-PLACE kvW transform, d-quarter granularity (proven round 3).
//   Block (qd, bz) owns rows d in [64qd, 64qd+64) of kv0[bz]: reads ONLY that
//   region (+WvT), overwrites it as kvWT'[c][d_local] = kv0@Wv + bv fold.
// Race-free: single owner per region; staging reads complete before epilogue.
// ---------------------------------------------------------------------------
__global__ __launch_bounds__(256) void k_kvw_inplace(
    ushort* kv0, const ushort* __restrict__ WvT,
    const float* __restrict__ bv) {
  const int qd = blockIdx.x;  // d-quarter (0..3)
  const int bz = blockIdx.y;  // b*N+n
  const int tid = threadIdx.x;
  const int l = tid & 63, w = tid >> 6;
  const int lane16 = l & 15, quad = l >> 4;

  __shared__ ushort ldsA[64 * 72];   // kv0 rows d_local x e-chunk
  __shared__ ushort ldsB[256 * 72];  // WvT rows c x e-chunk

  float4v acc[4][4];
#pragma unroll
  for (int i = 0; i < 4; ++i)
#pragma unroll
    for (int j = 0; j < 4; ++j) acc[i][j] = (float4v)0.0f;

  ushort* base = kv0 + (size_t)bz * (D_ * D_) + qd * (64 * D_);

  for (int ec = 0; ec < D_; ec += 64) {
    __syncthreads();
#pragma unroll
    for (int it = 0; it < 2; ++it) {  // A: 64 x 64
      int id = it * 256 + tid;
      int rd = id >> 3, cc = (id & 7) * 8;
      *(uint4*)(&ldsA[rd * 72 + cc]) =
          *(const uint4*)(base + rd * D_ + ec + cc);
    }
#pragma unroll
    for (int it = 0; it < 8; ++it) {  // B: 256 x 64
      int id = it * 256 + tid;
      int rd = id >> 3, cc = (id & 7) * 8;
      *(uint4*)(&ldsB[rd * 72 + cc]) =
          *(const uint4*)(WvT + rd * D_ + ec + cc);
    }
    __syncthreads();
#pragma unroll
    for (int kc = 0; kc < 64; kc += 32) {
      int ko = kc + quad * 8;
      short8 a[4], b[4];
#pragma unroll
      for (int i = 0; i < 4; ++i)
        a[i] = *(const short8*)(&ldsA[(i * 16 + lane16) * 72 + ko]);
#pragma unroll
      for (int j = 0; j < 4; ++j)
        b[j] = *(const short8*)(&ldsB[(w * 64 + j * 16 + lane16) * 72 + ko]);
#pragma unroll
      for (int i = 0; i < 4; ++i)
#pragma unroll
        for (int j = 0; j < 4; ++j)
          acc[i][j] = __builtin_amdgcn_mfma_f32_16x16x32_bf16(a[i], b[j],
                                                              acc[i][j], 0, 0, 0);
    }
  }
  // epilogue: overwrite own region as [c][d_local] (64-wide rows)
#pragma unroll
  for (int i = 0; i < 4; ++i) {
#pragma unroll
    for (int j = 0; j < 4; ++j) {
      int c = w * 64 + j * 16 + lane16;
      int d0 = i * 16 + quad * 4;
      float bvc = bv[c];
      ushort4 p;
      p.x = f2bf(acc[i][j][0] + bvc);
      p.y = f2bf(acc[i][j][1] + bvc);
      p.z = f2bf(acc[i][j][2] + bvc);
      p.w = f2bf(acc[i][j][3] + bvc);
      *(ushort4*)(base + c * 64 + d0) = p;
    }
  }
}

// ---------------------------------------------------------------------------
// Kernel 6: out[bz][s][c] = sum_d qb[n][s][d] * kvW'[bz](c,d)   (fp32 out)
// kvW' quarter-major: (c,d) at bz*65536 + (d>>6)*16384 + c*64 + (d&63).
// Tile 128x128; XCD swizzle co-locates the 8 tiles of one bz.
// ---------------------------------------------------------------------------
__global__ __launch_bounds__(256) void k_out(
    const ushort* __restrict__ qb, const ushort* __restrict__ kvw,
    float* __restrict__ out) {
  const int f = blockIdx.x;                 // 0..3071 (3072 % 8 == 0)
  const int wk = (f & 7) * 384 + (f >> 3);  // bijective XCD swizzle
  const int bx = wk & 3;         // s-tile (0..3)
  const int by = (wk >> 2) & 1;  // c-tile (0..1)
  const int bz = wk >> 3;        // b*N+n
  const int n = bz % N_;
  const int tid = threadIdx.x;
  const int l = tid & 63, w = tid >> 6;
  const int wm = w & 1, wn = w >> 1;
  const int lane16 = l & 15, quad = l >> 4;

  __shared__ ushort ldsA[128 * 72];  // qb tile   [s_local][d_local]
  __shared__ ushort ldsB[128 * 72];  // kvW' tile [c_local][d_local]

  float4v acc[4][4];
#pragma unroll
  for (int i = 0; i < 4; ++i)
#pragma unroll
    for (int j = 0; j < 4; ++j) acc[i][j] = (float4v)0.0f;

  const ushort* abase = qb + (size_t)n * S_ * D_ + bx * 128 * D_;
  const ushort* bbase = kvw + (size_t)bz * D_ * D_;

  for (int dc = 0; dc < D_; dc += 64) {
    __syncthreads();
#pragma unroll
    for (int it = 0; it < 4; ++it) {
      int id = it * 256 + tid;
      int rd = id >> 3, cc = (id & 7) * 8;
      *(uint4*)(&ldsA[rd * 72 + cc]) =
          *(const uint4*)(abase + rd * D_ + dc + cc);
    }
#pragma unroll
    for (int it = 0; it < 4; ++it) {
      int id = it * 256 + tid;
      int rd = id >> 3, cc = (id & 7) * 8;  // rd = c_local; dc&63 == 0
      *(uint4*)(&ldsB[rd * 72 + cc]) =
          *(const uint4*)(bbase + (dc >> 6) * 16384 + (by * 128 + rd) * 64 +
                          cc);
    }
    __syncthreads();
#pragma unroll
    for (int kc = 0; kc < 64; kc += 32) {
      int ko = kc + quad * 8;
      short8 a[4], b[4];
#pragma unroll
      for (int i = 0; i < 4; ++i)
        a[i] = *(const short8*)(&ldsA[(wm * 64 + i * 16 + lane16) * 72 + ko]);
#pragma unroll
      for (int j = 0; j < 4; ++j)
        b[j] = *(const short8*)(&ldsB[(wn * 64 + j * 16 + lane16) * 72 + ko]);
#pragma unroll
      for (int i = 0; i < 4; ++i)
#pragma unroll
        for (int j = 0; j < 4; ++j)
          acc[i][j] = __builtin_amdgcn_mfma_f32_16x16x32_bf16(a[i], b[j],
                                                              acc[i][j], 0, 0, 0);
    }
  }
  float* obase = out + (size_t)bz * S_ * D_;
#pragma unroll
  for (int i = 0; i < 4; ++i) {
#pragma unroll
    for (int j = 0; j < 4; ++j) {
      int s0 = bx * 128 + wm * 64 + i * 16 + quad * 4;
      int c = by * 128 + wn * 64 + j * 16 + lane16;
#pragma unroll
      for (int r = 0; r < 4; ++r)
        obase[(s0 + r) * D_ + c] = acc[i][j][r];
    }
  }
}

// ---------------------------------------------------------------------------
extern "C" void kernel_launch(void* const* d_in, const int* in_sizes, int n_in,
                              void* d_out, int out_size, void* d_ws,
                              size_t ws_size, hipStream_t stream) {
  const float* value = (const float*)d_in[0];  // [B,N,S,D]
  const float* emb   = (const float*)d_in[1];  // [N,S,A]
  const float* Wqk   = (const float*)d_in[2];  // [A,D]
  const float* bqk   = (const float*)d_in[3];  // [D]
  const float* Wv    = (const float*)d_in[4];  // [D,D]
  const float* bv    = (const float*)d_in[5];  // [D]
  float* out = (float*)d_out;

  // ws layout (bytes) — total 63,045,632 B (proven size):
  //   qk fp32   [0,         6291456)
  //   qb bf16   [6291456,   9437184)
  //   kTb bf16  [9437184,   12582912)
  //   kv0/kvWT  [12582912,  62914560)   k4 out [bz][d][e]; k5 rewrites in-place
  //   WvT bf16  [62914560,  63045632)
  char* ws = (char*)d_ws;
  float*  qk  = (float*)ws;
  ushort* qb  = (ushort*)(ws + 6291456);
  ushort* kTb = (ushort*)(ws + 9437184);
  ushort* kv0 = (ushort*)(ws + 12582912);
  ushort* WvT = (ushort*)(ws + 62914560);

  k_qk_softmax_q<<<dim3(N_ * S_ / 8), 256, 0, stream>>>(emb, Wqk, bqk, qk, qb);
  k_softmax_kT<<<dim3(16, N_), 256, 0, stream>>>(qk, kTb);
  k_wvt<<<dim3(D_), 256, 0, stream>>>(Wv, WvT);
  k_kv0<<<dim3(4 * B_ * N_), 512, 0, stream>>>(kTb, value, kv0);
  k_kvw_inplace<<<dim3(4, B_ * N_), 256, 0, stream>>>(kv0, WvT, bv);
  k_out<<<dim3(4 * 2 * B_ * N_), 256, 0, stream>>>(qb, kv0, out);
}